// Round 10
// baseline (102.433 us; speedup 1.0000x reference)
//
#include <hip/hip_runtime.h>

#define N_NODES 512
#define N_EDGES (512 * 512)

typedef _Float16 f16x8 __attribute__((ext_vector_type(8)));
typedef float f32x4 __attribute__((ext_vector_type(4)));

__device__ __forceinline__ unsigned pkf16(float a, float b) {
  return __builtin_bit_cast(unsigned, __builtin_amdgcn_cvt_pkrtz(a, b));
}

// ---------------- histogram of dst ----------------
__global__ void hist_k(const int* __restrict__ dst, int* __restrict__ counts) {
  __shared__ int lh[N_NODES];
  for (int i = threadIdx.x; i < N_NODES; i += blockDim.x) lh[i] = 0;
  __syncthreads();
  const int stride = gridDim.x * blockDim.x;
  for (int e = blockIdx.x * blockDim.x + threadIdx.x; e < N_EDGES; e += stride)
    atomicAdd(&lh[dst[e]], 1);
  __syncthreads();
  for (int i = threadIdx.x; i < N_NODES; i += blockDim.x) {
    int c = lh[i];
    if (c) atomicAdd(&counts[i], c);
  }
}

// ---------------- exclusive scan over 512 counts ----------------
__global__ void scan_k(const int* __restrict__ counts, int* __restrict__ offsets,
                       int* __restrict__ cursor) {
  __shared__ int tmp[N_NODES];
  const int t = threadIdx.x;
  const int c = counts[t];
  tmp[t] = c;
  __syncthreads();
  for (int d = 1; d < N_NODES; d <<= 1) {
    int add = (t >= d) ? tmp[t - d] : 0;
    __syncthreads();
    tmp[t] += add;
    __syncthreads();
  }
  offsets[t + 1] = tmp[t];
  if (t == 0) offsets[0] = 0;
  cursor[t] = tmp[t] - c;
}

// ---- scatter: CSR-sort edges, writing PACKED f16 ea (+bias-enable) and src ----
__launch_bounds__(512)
__global__ void scatter3_k(const float* __restrict__ ea, const int* __restrict__ src,
                           const int* __restrict__ dst, int* __restrict__ cursor,
                           uint4* __restrict__ eaPk, int* __restrict__ srcSorted) {
  __shared__ int lhist[N_NODES];
  __shared__ int gb[N_NODES];
  const int t = threadIdx.x;
  const int c0 = blockIdx.x * 4096;
  lhist[t] = 0;
  __syncthreads();
  int d[8], r[8];
#pragma unroll
  for (int j = 0; j < 8; j++) {
    d[j] = dst[c0 + t + j * 512];
    r[j] = atomicAdd(&lhist[d[j]], 1);
  }
  __syncthreads();
  gb[t] = atomicAdd(&cursor[t], lhist[t]);
  __syncthreads();
#pragma unroll
  for (int j = 0; j < 8; j++) {
    const int e = c0 + t + j * 512;
    const int pos = gb[d[j]] + r[j];
    const float2* er = reinterpret_cast<const float2*>(ea + (size_t)e * 6);
    const float2 a0 = er[0], a1 = er[1], a2 = er[2];
    uint4 pk;
    pk.x = pkf16(a0.x, a0.y);
    pk.y = pkf16(a1.x, a1.y);
    pk.z = pkf16(a2.x, a2.y);
    pk.w = 0x00003C00u;  // k=6: (1.0h, 0h) -> bias row enable
    eaPk[pos] = pk;
    srcSorted[pos] = src[e];
  }
}

// ---- pack W+bias as MFMA A-rows, i-uniform padded tile layouts, one launch ----
__global__ void packAll2_k(const float* __restrict__ W1, const float* __restrict__ b1,
                           const float* __restrict__ W2, const float* __restrict__ b2,
                           const float* __restrict__ W3, const float* __restrict__ b3,
                           uint4* __restrict__ wpk) {
  const int t = blockIdx.x * 256 + threadIdx.x;
  uint4 r = make_uint4(0u, 0u, 0x00000000u, pkf16(-1.f, 0.f));  // pad: w=0, bias=-1
  if (t < 48) {
    if (t < 36) {
      r.x = pkf16(W1[0 * 36 + t], W1[1 * 36 + t]);
      r.y = pkf16(W1[2 * 36 + t], W1[3 * 36 + t]);
      r.z = pkf16(W1[4 * 36 + t], W1[5 * 36 + t]);
      r.w = pkf16(b1[t], 0.f);
    }
    wpk[t] = r;
  } else if (t < 1200) {
    const int q = t - 48;
    const int tile = q >> 4, row = q & 15;
    const int i = tile >> 1, o = ((tile & 1) << 4) + row;
    if (o < 24) {
      const int p = i * 24 + o;
      r.x = pkf16(W2[0 * 864 + p], W2[1 * 864 + p]);
      r.y = pkf16(W2[2 * 864 + p], W2[3 * 864 + p]);
      r.z = pkf16(W2[4 * 864 + p], W2[5 * 864 + p]);
      r.w = pkf16(b2[p], 0.f);
    }
    wpk[t] = r;
  } else if (t < 1328) {
    const int q = t - 1200;
    const int tile = q >> 4, row = q & 15;
    if (row < 15) {
      const int i = 3 * tile + row / 5;
      const int o = row % 5;
      const int p = i * 5 + o;
      r.x = pkf16(W3[0 * 120 + p], W3[1 * 120 + p]);
      r.y = pkf16(W3[2 * 120 + p], W3[3 * 120 + p]);
      r.z = pkf16(W3[4 * 120 + p], W3[5 * 120 + p]);
      r.w = pkf16(b3[p], 0.f);
    }
    wpk[t] = r;
  }
}

// ======== layer 1: IN=1, OUT=36 (3 tiles). Wave-indep groups, prefetched. ========
__launch_bounds__(512, 4)
__global__ void conv1_k(const float* __restrict__ x,
                        const uint4* __restrict__ eaPk, const int* __restrict__ srcSorted,
                        const int* __restrict__ offsets, const uint4* __restrict__ Wpk,
                        const float* __restrict__ root, const float* __restrict__ bias,
                        float* __restrict__ hnext) {
  __shared__ float hS[N_NODES];
  __shared__ float pAcc[8][48];
  const int tid = threadIdx.x, w = tid >> 6, l = tid & 63;
  const int node = blockIdx.x;
  const int off = offsets[node], cnt = offsets[node + 1] - off;
  const int col = l & 15, crow = (l >> 4) << 2;

  if (tid < N_NODES) hS[tid] = x[tid];

  f16x8 afr[3];
  f32x4 acc[3];
#pragma unroll
  for (int t = 0; t < 3; t++) {
    uint4 wv = make_uint4(0u, 0u, 0u, 0u);
    if (l < 16) wv = Wpk[t * 16 + l];
    afr[t] = __builtin_bit_cast(f16x8, wv);
    acc[t] = (f32x4){0.f, 0.f, 0.f, 0.f};
  }
  __syncthreads();

  const int NG = (cnt + 15) >> 4;
  const f32x4 zero4 = {0.f, 0.f, 0.f, 0.f};

  uint4 bv_c = make_uint4(0u, 0u, 0u, 0u);
  int s_c = 0;
  auto gload = [&](int g) {
    const int pos = g * 16 + col;
    const bool v = pos < cnt;
    s_c = v ? srcSorted[off + pos] : 0;
    bv_c = make_uint4(0u, 0u, 0u, 0u);
    if (l < 16 && v) bv_c = eaPk[off + pos];
  };

  if (w < NG) gload(w);
  for (int g = w; g < NG; g += 8) {
    const f16x8 bfr = __builtin_bit_cast(f16x8, bv_c);
    const float hv = hS[s_c];
    if (g + 8 < NG) gload(g + 8);
    f32x4 tc = __builtin_amdgcn_mfma_f32_16x16x32_f16(afr[0], bfr, zero4, 0, 0, 0);
#pragma unroll
    for (int t = 0; t < 3; t++) {
      f32x4 tn;
      if (t < 2) tn = __builtin_amdgcn_mfma_f32_16x16x32_f16(afr[t + 1], bfr, zero4, 0, 0, 0);
#pragma unroll
      for (int r = 0; r < 4; r++)
        acc[t][r] = fmaf(fmaxf(tc[r], 0.f), hv, acc[t][r]);
      if (t < 2) tc = tn;
    }
  }
#pragma unroll
  for (int t = 0; t < 3; t++)
#pragma unroll
    for (int r = 0; r < 4; r++) {
      float vv = acc[t][r];
      vv += __shfl_xor(vv, 1); vv += __shfl_xor(vv, 2);
      vv += __shfl_xor(vv, 4); vv += __shfl_xor(vv, 8);
      if (col == 0) pAcc[w][t * 16 + crow + r] = vv;
    }
  __syncthreads();
  if (tid < 36) {
    const int o = tid;
    float sagg = 0.f;
#pragma unroll
    for (int ww = 0; ww < 8; ww++) sagg += pAcc[ww][o];
    const float agg = sagg / fmaxf((float)cnt, 1.f);
    const float r2 = fmaf(hS[node], root[o], bias[o]);
    hnext[node * 36 + o] = fmaxf(agg + r2, 0.f);
  }
}

// ======== layer 2: IN=36, OUT=24 (72 padded tiles = 36 i-pairs). Pipelined. ========
__launch_bounds__(512, 4)
__global__ void conv2_k(const float* __restrict__ hprev,
                        const uint4* __restrict__ eaPk, const int* __restrict__ srcSorted,
                        const int* __restrict__ offsets, const uint4* __restrict__ Wpk,
                        const float* __restrict__ root, const float* __restrict__ bias,
                        float* __restrict__ hnext) {
  __shared__ float hS[N_NODES * 37];
  __shared__ float pAcc[1152];
  const int tid = threadIdx.x, w = tid >> 6, l = tid & 63;
  const int node = blockIdx.x;
  const int off = offsets[node], cnt = offsets[node + 1] - off;
  const int col = l & 15, crow = (l >> 4) << 2;

  for (int n = tid; n < N_NODES * 36; n += 512) hS[n + n / 36] = hprev[n];

  f16x8 afr[5][2];
  f32x4 acc[5][2];
  int hidx[5];
#pragma unroll
  for (int jp = 0; jp < 5; jp++) {
    const int tp = w + 8 * jp;
    hidx[jp] = (tp < 36) ? tp : 0;
#pragma unroll
    for (int hh = 0; hh < 2; hh++) {
      uint4 wv = make_uint4(0u, 0u, 0u, 0u);
      if (tp < 36 && l < 16) wv = Wpk[(2 * tp + hh) * 16 + l];
      afr[jp][hh] = __builtin_bit_cast(f16x8, wv);
      acc[jp][hh] = (f32x4){0.f, 0.f, 0.f, 0.f};
    }
  }
  __syncthreads();

  const int NG = (cnt + 15) >> 4;
  const f32x4 zero4 = {0.f, 0.f, 0.f, 0.f};

  uint4 bv_c = make_uint4(0u, 0u, 0u, 0u);
  int s_c = 0;
  auto gload = [&](int g) {
    const int pos = g * 16 + col;
    const bool v = pos < cnt;
    s_c = v ? srcSorted[off + pos] : 0;
    bv_c = make_uint4(0u, 0u, 0u, 0u);
    if (l < 16 && v) bv_c = eaPk[off + pos];
  };

  if (NG > 0) gload(0);
  for (int g = 0; g < NG; g++) {
    // hoisted h reads for current group (5 outstanding ds_reads)
    const int sb = s_c * 37;
    float hcur[5];
#pragma unroll
    for (int jp = 0; jp < 5; jp++) hcur[jp] = hS[sb + hidx[jp]];
    const f16x8 bfr = __builtin_bit_cast(f16x8, bv_c);
    if (g + 1 < NG) gload(g + 1);  // prefetch next group's globals
    // MFMA 2-deep rotation: issue pair jp+1 before consuming pair jp
    f32x4 t0 = __builtin_amdgcn_mfma_f32_16x16x32_f16(afr[0][0], bfr, zero4, 0, 0, 0);
    f32x4 t1 = __builtin_amdgcn_mfma_f32_16x16x32_f16(afr[0][1], bfr, zero4, 0, 0, 0);
#pragma unroll
    for (int jp = 0; jp < 5; jp++) {
      f32x4 n0, n1;
      if (jp < 4) {
        n0 = __builtin_amdgcn_mfma_f32_16x16x32_f16(afr[jp + 1][0], bfr, zero4, 0, 0, 0);
        n1 = __builtin_amdgcn_mfma_f32_16x16x32_f16(afr[jp + 1][1], bfr, zero4, 0, 0, 0);
      }
      const float hv = hcur[jp];
#pragma unroll
      for (int r = 0; r < 4; r++) {
        acc[jp][0][r] = fmaf(fmaxf(t0[r], 0.f), hv, acc[jp][0][r]);
        acc[jp][1][r] = fmaf(fmaxf(t1[r], 0.f), hv, acc[jp][1][r]);
      }
      if (jp < 4) { t0 = n0; t1 = n1; }
    }
  }

#pragma unroll
  for (int jp = 0; jp < 5; jp++) {
    const int tp = w + 8 * jp;
    if (tp < 36) {
#pragma unroll
      for (int hh = 0; hh < 2; hh++)
#pragma unroll
        for (int r = 0; r < 4; r++) {
          float vv = acc[jp][hh][r];
          vv += __shfl_xor(vv, 1); vv += __shfl_xor(vv, 2);
          vv += __shfl_xor(vv, 4); vv += __shfl_xor(vv, 8);
          if (col == 0) pAcc[tp * 32 + hh * 16 + crow + r] = vv;
        }
    }
  }
  __syncthreads();
  if (tid < 24) {
    const int o = tid;
    float sagg = 0.f;
    for (int i = 0; i < 36; i++) sagg += pAcc[i * 32 + o];
    const float agg = sagg / fmaxf((float)cnt, 1.f);
    float r2 = bias[o];
    for (int i = 0; i < 36; i++) r2 = fmaf(hS[node * 37 + i], root[i * 24 + o], r2);
    hnext[node * 24 + o] = fmaxf(agg + r2, 0.f);
  }
}

// ======== layer 3: IN=24, OUT=5 (8 tiles). Wave-indep groups, pipelined. ========
__launch_bounds__(512, 4)
__global__ void conv3_k(const float* __restrict__ hprev,
                        const uint4* __restrict__ eaPk, const int* __restrict__ srcSorted,
                        const int* __restrict__ offsets, const uint4* __restrict__ Wpk,
                        const float* __restrict__ root, const float* __restrict__ bias,
                        float* __restrict__ hnext) {
  __shared__ float hS[N_NODES * 25];
  __shared__ float pAcc[8][128];
  const int tid = threadIdx.x, w = tid >> 6, l = tid & 63;
  const int node = blockIdx.x;
  const int off = offsets[node], cnt = offsets[node + 1] - off;
  const int col = l & 15, crow = (l >> 4) << 2;

  for (int n = tid; n < N_NODES * 24; n += 512) hS[n + n / 24] = hprev[n];

  f16x8 afr[8];
  f32x4 acc[8];
#pragma unroll
  for (int t = 0; t < 8; t++) {
    uint4 wv = make_uint4(0u, 0u, 0u, 0u);
    if (l < 16) wv = Wpk[t * 16 + l];
    afr[t] = __builtin_bit_cast(f16x8, wv);
    acc[t] = (f32x4){0.f, 0.f, 0.f, 0.f};
  }
  __syncthreads();

  const int NG = (cnt + 15) >> 4;
  const f32x4 zero4 = {0.f, 0.f, 0.f, 0.f};

  uint4 bv_c = make_uint4(0u, 0u, 0u, 0u);
  int s_c = 0;
  auto gload = [&](int g) {
    const int pos = g * 16 + col;
    const bool v = pos < cnt;
    s_c = v ? srcSorted[off + pos] : 0;
    bv_c = make_uint4(0u, 0u, 0u, 0u);
    if (l < 16 && v) bv_c = eaPk[off + pos];
  };

  if (w < NG) gload(w);
  for (int g = w; g < NG; g += 8) {
    const int sb = s_c * 25;
    float h0[8], h1[8], h2[8];
#pragma unroll
    for (int t = 0; t < 8; t++) {
      h0[t] = hS[sb + 3 * t];
      h1[t] = hS[sb + 3 * t + 1];
      h2[t] = hS[sb + 3 * t + 2];
    }
    const f16x8 bfr = __builtin_bit_cast(f16x8, bv_c);
    if (g + 8 < NG) gload(g + 8);
    f32x4 tc = __builtin_amdgcn_mfma_f32_16x16x32_f16(afr[0], bfr, zero4, 0, 0, 0);
#pragma unroll
    for (int t = 0; t < 8; t++) {
      f32x4 tn;
      if (t < 7) tn = __builtin_amdgcn_mfma_f32_16x16x32_f16(afr[t + 1], bfr, zero4, 0, 0, 0);
#pragma unroll
      for (int r = 0; r < 4; r++) {
        const int row = crow + r;
        const float hv = (row < 5) ? h0[t] : ((row < 10) ? h1[t] : h2[t]);
        acc[t][r] = fmaf(fmaxf(tc[r], 0.f), hv, acc[t][r]);
      }
      if (t < 7) tc = tn;
    }
  }
#pragma unroll
  for (int t = 0; t < 8; t++)
#pragma unroll
    for (int r = 0; r < 4; r++) {
      float vv = acc[t][r];
      vv += __shfl_xor(vv, 1); vv += __shfl_xor(vv, 2);
      vv += __shfl_xor(vv, 4); vv += __shfl_xor(vv, 8);
      if (col == 0) pAcc[w][t * 16 + crow + r] = vv;
    }
  __syncthreads();
  if (tid < 128) {
    float s8 = 0.f;
#pragma unroll
    for (int ww = 0; ww < 8; ww++) s8 += pAcc[ww][tid];
    pAcc[0][tid] = s8;
  }
  __syncthreads();
  if (tid < 5) {
    const int o = tid;
    float sagg = 0.f;
    for (int i = 0; i < 24; i++) {
      const int t = i / 3, iloc = i - 3 * t;
      sagg += pAcc[0][t * 16 + iloc * 5 + o];
    }
    const float agg = sagg / fmaxf((float)cnt, 1.f);
    float r2 = bias[o];
    for (int i = 0; i < 24; i++) r2 = fmaf(hS[node * 25 + i], root[i * 5 + o], r2);
    hnext[node * 5 + o] = fmaxf(agg + r2, 0.f);
  }
}

// ---------------- CBT: pairwise L1 over h3 [512, 5] ----------------
__global__ void cbt_k(const float* __restrict__ h3, float* __restrict__ out) {
  __shared__ float sh[N_NODES * 5];
  for (int i = threadIdx.x; i < N_NODES * 5; i += blockDim.x) sh[i] = h3[i];
  __syncthreads();
  const int a = blockIdx.x;
  float ha0 = sh[a * 5 + 0], ha1 = sh[a * 5 + 1], ha2 = sh[a * 5 + 2],
        ha3 = sh[a * 5 + 3], ha4 = sh[a * 5 + 4];
  for (int b = threadIdx.x; b < N_NODES; b += blockDim.x) {
    float s = fabsf(sh[b * 5 + 0] - ha0) + fabsf(sh[b * 5 + 1] - ha1) +
              fabsf(sh[b * 5 + 2] - ha2) + fabsf(sh[b * 5 + 3] - ha3) +
              fabsf(sh[b * 5 + 4] - ha4);
    out[a * N_NODES + b] = s;
  }
}

extern "C" void kernel_launch(void* const* d_in, const int* in_sizes, int n_in,
                              void* d_out, int out_size, void* d_ws, size_t ws_size,
                              hipStream_t stream) {
  const float* x     = (const float*)d_in[0];
  const float* ea    = (const float*)d_in[1];
  const int*   ei    = (const int*)d_in[2];
  const float* W1    = (const float*)d_in[3];
  const float* b1    = (const float*)d_in[4];
  const float* root1 = (const float*)d_in[5];
  const float* bias1 = (const float*)d_in[6];
  const float* W2    = (const float*)d_in[7];
  const float* b2    = (const float*)d_in[8];
  const float* root2 = (const float*)d_in[9];
  const float* bias2 = (const float*)d_in[10];
  const float* W3    = (const float*)d_in[11];
  const float* b3    = (const float*)d_in[12];
  const float* root3 = (const float*)d_in[13];
  const float* bias3 = (const float*)d_in[14];

  const int* src = ei;
  const int* dst = ei + N_EDGES;

  char* ws = (char*)d_ws;
  int* counts    = (int*)(ws + 0);
  int* offsets   = (int*)(ws + 4096);
  int* cursor    = (int*)(ws + 8192);
  uint4* eaPk    = (uint4*)(ws + 16384);                 // 4 MB
  int* srcSorted = (int*)(ws + 16384 + N_EDGES * 16);    // 1 MB
  char* p2       = ws + 16384 + N_EDGES * 20;
  float* h1      = (float*)(p2);
  float* h2_     = h1 + N_NODES * 36;
  float* h3      = h2_ + N_NODES * 24;
  uint4* wpkAll  = (uint4*)(p2 + 256 * 1024);
  uint4* wpk1    = wpkAll;
  uint4* wpk2    = wpkAll + 48;
  uint4* wpk3    = wpkAll + 1200;

  hipMemsetAsync(counts, 0, N_NODES * sizeof(int), stream);
  hist_k<<<64, 256, 0, stream>>>(dst, counts);
  scan_k<<<1, N_NODES, 0, stream>>>(counts, offsets, cursor);
  scatter3_k<<<N_EDGES / 4096, 512, 0, stream>>>(ea, src, dst, cursor, eaPk, srcSorted);
  packAll2_k<<<6, 256, 0, stream>>>(W1, b1, W2, b2, W3, b3, wpkAll);

  conv1_k<<<N_NODES, 512, 0, stream>>>(x, eaPk, srcSorted, offsets, wpk1, root1, bias1, h1);
  conv2_k<<<N_NODES, 512, 0, stream>>>(h1, eaPk, srcSorted, offsets, wpk2, root2, bias2, h2_);
  conv3_k<<<N_NODES, 512, 0, stream>>>(h2_, eaPk, srcSorted, offsets, wpk3, root3, bias3, h3);

  cbt_k<<<N_NODES, 256, 0, stream>>>(h3, (float*)d_out);
}